// Round 19
// baseline (281.570 us; speedup 1.0000x reference)
//
#include <hip/hip_runtime.h>
#include <hip/hip_bf16.h>

typedef __attribute__((ext_vector_type(4))) float f32x4;
typedef __attribute__((ext_vector_type(4))) int i32x4;
typedef __attribute__((ext_vector_type(4))) unsigned int u32x4;
typedef __attribute__((ext_vector_type(8))) __bf16 bf16x8;
typedef __attribute__((ext_vector_type(4))) __bf16 bf16x4;

#define SDIM 2048
#define DDIM 512
#define HH 8
#define DH 64

static __device__ __forceinline__ f32x4 mfma_raw(bf16x8 a, bf16x8 b, f32x4 c) {
  return __builtin_amdgcn_mfma_f32_16x16x32_bf16(a, b, c, 0, 0, 0);
}

// Operand-order-corrected MFMA: acc[c][r] = D[row = tile + lg*4 + r][col = lr],
// row side fed by FIRST logical operand under either hardware convention.
template <bool C1>
static __device__ __forceinline__ f32x4 mf(bf16x8 a, bf16x8 b, f32x4 c) {
  return C1 ? mfma_raw(a, b, c) : mfma_raw(b, a, c);
}

static __device__ __forceinline__ unsigned pack_bf16(float a, float b) {
  __bf16 x = (__bf16)a, y = (__bf16)b;
  unsigned short ux = __builtin_bit_cast(unsigned short, x);
  unsigned short uy = __builtin_bit_cast(unsigned short, y);
  return ((unsigned)uy << 16) | (unsigned)ux;
}

// ---- stage A: covm fold -> bf16, lane-permuted (blocks 0..8191) + LayerNorm (8192..9215)
//      + wtrans (9216..9471). Permutation within each 256-key chunk:
//      orig o = c*16 + lg*4 + r  ->  new o = lg*64 + c*4 + r   (c=o>>4, lg=(o>>2)&3)
__global__ __launch_bounds__(256) void stageA_kernel(const float* __restrict__ cov,
                                                     const int* __restrict__ mask,
                                                     __bf16* __restrict__ covm,
                                                     const float* __restrict__ q,
                                                     const float* __restrict__ gamma,
                                                     const float* __restrict__ beta,
                                                     __bf16* __restrict__ qn,
                                                     const float* __restrict__ w0,
                                                     const float* __restrict__ w1,
                                                     const float* __restrict__ w2,
                                                     const float* __restrict__ w3,
                                                     __bf16* __restrict__ t0,
                                                     __bf16* __restrict__ t1,
                                                     __bf16* __restrict__ t2,
                                                     __bf16* __restrict__ t3,
                                                     int* __restrict__ flag) {
  __shared__ float tile[64][65];
  int bid = blockIdx.x;
  if (bid < 8192) {
    size_t i = ((size_t)bid * 256 + threadIdx.x) * 4;
    f32x4 c = *(const f32x4*)(cov + i);
    i32x4 m = *(const i32x4*)(mask + i);
    unsigned o = (unsigned)(i & 255);       // aligned-4, so r component is 0
    unsigned c16 = o >> 4;
    unsigned lgp = (o >> 2) & 3;
    size_t dst = (i & ~(size_t)255) + lgp * 64 + c16 * 4;
    bf16x4 ob;
#pragma unroll
    for (int r = 0; r < 4; ++r) ob[r] = (__bf16)((m[r] == 0) ? -1e38f : c[r]);
    *(bf16x4*)(covm + dst) = ob;
    return;
  }
  if (bid < 9216) {
    int lb = bid - 8192;
    if (lb == 0 && threadIdx.x < 64) {
      float av = (float)(threadIdx.x & 15);
      float bv = av * av;
      bf16x8 a, b;
#pragma unroll
      for (int i = 0; i < 8; ++i) { a[i] = (__bf16)av; b[i] = (__bf16)bv; }
      f32x4 d = {};
      d = mfma_raw(a, b, d);
      if (threadIdx.x == 17) *flag = (d[0] == 128.0f) ? 1 : 2;
    }
    int row = lb * 4 + (threadIdx.x >> 6);
    int lane = threadIdx.x & 63;
    const float* qr = q + (size_t)row * DDIM + lane * 8;
    f32x4 x0 = *(const f32x4*)qr;
    f32x4 x1 = *(const f32x4*)(qr + 4);
    float s = 0.f;
#pragma unroll
    for (int i = 0; i < 4; ++i) s += x0[i] + x1[i];
#pragma unroll
    for (int off = 32; off; off >>= 1) s += __shfl_xor(s, off);
    float mu = s * (1.f / DDIM);
    float vs = 0.f;
#pragma unroll
    for (int i = 0; i < 4; ++i) {
      float d0 = x0[i] - mu, d1 = x1[i] - mu;
      vs += d0 * d0 + d1 * d1;
    }
#pragma unroll
    for (int off = 32; off; off >>= 1) vs += __shfl_xor(vs, off);
    float inv = rsqrtf(vs * (1.f / DDIM) + 1e-6f);
    const float* g = gamma + lane * 8;
    const float* be = beta + lane * 8;
    bf16x8 o;
#pragma unroll
    for (int i = 0; i < 8; ++i) {
      float xv = (i < 4) ? x0[i] : x1[i - 4];
      o[i] = (__bf16)((xv - mu) * inv * g[i] + be[i]);
    }
    *(bf16x8*)(qn + (size_t)row * DDIM + lane * 8) = o;
    return;
  }
  int wb = bid - 9216;
  int which = wb >> 6;
  int rem = wb & 63;
  int n0 = (rem & 7) * 64;
  int k0 = (rem >> 3) * 64;
  const float* w = which == 0 ? w0 : which == 1 ? w1 : which == 2 ? w2 : w3;
  __bf16* t = which == 0 ? t0 : which == 1 ? t1 : which == 2 ? t2 : t3;
  int tx = threadIdx.x & 63, ty = threadIdx.x >> 6;
#pragma unroll
  for (int j = 0; j < 16; ++j) {
    int kk = ty * 16 + j;
    tile[kk][tx] = w[(size_t)(k0 + kk) * DDIM + n0 + tx];
  }
  __syncthreads();
#pragma unroll
  for (int j = 0; j < 16; ++j) {
    int n = ty * 16 + j;
    t[(size_t)(n0 + n) * DDIM + k0 + tx] = (__bf16)tile[tx][n];
  }
}

// ---- projections v2: each block computes a full 64-row x 512-col stripe.
// A fragments cached in registers (read A exactly once); loop over 8 head n-tiles.
// qh[b,h,s,dk] (scaled 1/(8*(lam+1))), kh[b,h,s,dk], vT[b,h,dv,s]
template <bool C1>
static __device__ __forceinline__ void proj_body(const __bf16* __restrict__ qn,
                                                 const float* __restrict__ kin,
                                                 const float* __restrict__ vin,
                                                 const __bf16* __restrict__ wqT,
                                                 const __bf16* __restrict__ wkT,
                                                 const __bf16* __restrict__ wvT,
                                                 const float* __restrict__ lam,
                                                 __bf16* __restrict__ qh,
                                                 __bf16* __restrict__ kh,
                                                 __bf16* __restrict__ vT,
                                                 __bf16* __restrict__ tr) {
  int which = blockIdx.y;
  int m0 = blockIdx.x * 64;
  int wid = threadIdx.x >> 6, lane = threadIdx.x & 63;
  int lr = lane & 15, lg = lane >> 4;
  int mrow = m0 + wid * 16;
  const __bf16* wT = which == 0 ? wqT : which == 1 ? wkT : wvT;
  // cache A fragments: row mrow+lr, k = kb*32 + lg*8 .. +8  (64 VGPRs)
  bf16x8 af[16];
  if (which == 0) {
#pragma unroll
    for (int kb = 0; kb < 16; ++kb)
      af[kb] = *(const bf16x8*)(qn + (size_t)(mrow + lr) * DDIM + kb * 32 + lg * 8);
  } else {
    const float* A = which == 1 ? kin : vin;
#pragma unroll
    for (int kb = 0; kb < 16; ++kb) {
      const float* src = A + (size_t)(mrow + lr) * DDIM + kb * 32 + lg * 8;
      f32x4 y0 = *(const f32x4*)src;
      f32x4 y1 = *(const f32x4*)(src + 4);
      bf16x8 a;
#pragma unroll
      for (int i = 0; i < 4; ++i) { a[i] = (__bf16)y0[i]; a[i + 4] = (__bf16)y1[i]; }
      af[kb] = a;
    }
  }
  int bq = m0 >> 11;
  int ss0 = m0 & 2047;
  for (int h = 0; h < 8; ++h) {
    int n0 = h * 64;
    f32x4 acc[4] = {};
#pragma unroll
    for (int kb = 0; kb < 16; ++kb) {
#pragma unroll
      for (int c = 0; c < 4; ++c) {
        bf16x8 bfrag = *(const bf16x8*)(wT + (size_t)(n0 + c * 16 + lr) * DDIM + kb * 32 + lg * 8);
        acc[c] = mf<C1>(af[kb], bfrag, acc[c]);
      }
    }
    // stage into LDS: qk path -> [m_local][dd]; v path -> [dd][m_local]; stride 72
    if (which == 0) {
      float sc = 1.f / (8.f * (lam[h] + 1.f));
#pragma unroll
      for (int c = 0; c < 4; ++c)
#pragma unroll
        for (int r = 0; r < 4; ++r)
          tr[(wid * 16 + lg * 4 + r) * 72 + c * 16 + lr] = (__bf16)(acc[c][r] * sc);
    } else if (which == 1) {
#pragma unroll
      for (int c = 0; c < 4; ++c)
#pragma unroll
        for (int r = 0; r < 4; ++r)
          tr[(wid * 16 + lg * 4 + r) * 72 + c * 16 + lr] = (__bf16)acc[c][r];
    } else {
#pragma unroll
      for (int c = 0; c < 4; ++c)
#pragma unroll
        for (int r = 0; r < 4; ++r)
          tr[(c * 16 + lr) * 72 + wid * 16 + lg * 4 + r] = (__bf16)acc[c][r];
    }
    __syncthreads();
    size_t bh2 = (size_t)bq * HH + h;
#pragma unroll
    for (int ii = 0; ii < 2; ++ii) {
      int row = (threadIdx.x >> 3) + ii * 32;
      int col = (threadIdx.x & 7) * 8;
      bf16x8 v8 = *(const bf16x8*)(tr + row * 72 + col);
      if (which == 2) {
        *(bf16x8*)(vT + (bh2 * DH + row) * SDIM + ss0 + col) = v8;
      } else {
        __bf16* dst = (which == 0 ? qh : kh);
        *(bf16x8*)(dst + (bh2 * SDIM + ss0 + row) * DH + col) = v8;
      }
    }
    __syncthreads();   // tr reused next h
  }
}

__global__ __launch_bounds__(256, 2) void proj_kernel(const __bf16* __restrict__ qn,
                                                      const float* __restrict__ kin,
                                                      const float* __restrict__ vin,
                                                      const __bf16* __restrict__ wqT,
                                                      const __bf16* __restrict__ wkT,
                                                      const __bf16* __restrict__ wvT,
                                                      const float* __restrict__ lam,
                                                      __bf16* __restrict__ qh,
                                                      __bf16* __restrict__ kh,
                                                      __bf16* __restrict__ vT,
                                                      const int* __restrict__ flag) {
  extern __shared__ __bf16 psm[];   // [64][72]
  if (*flag == 1) proj_body<true>(qn, kin, vin, wqT, wkT, wvT, lam, qh, kh, vT, psm);
  else            proj_body<false>(qn, kin, vin, wqT, wkT, wvT, lam, qh, kh, vT, psm);
}

// ---- FUSED: 512 thr (8 waves), KPW=256, 2 blocks/CU, 2 barriers. (r17 config)
// bf16 lane-permuted covm loaded inline in phase 2; attn stores interleaved into phase 4.
template <bool C1>
static __device__ __forceinline__ void fused_body(const __bf16* __restrict__ qh,
                                                  const __bf16* __restrict__ kh,
                                                  const __bf16* __restrict__ vT,
                                                  const __bf16* __restrict__ covm,
                                                  const float* __restrict__ lam,
                                                  float* __restrict__ attn,
                                                  __bf16* __restrict__ oh,
                                                  float* __restrict__ smem) {
  float* part  = smem;                   // [8][64] stride 17
  float* wredm = smem + 8 * 64 * 17;     // [8][16] wave max
  float* wreds = wredm + 128;            // [8][16] wave sum
  int bid = blockIdx.x;
  int xcd = bid & 7;
  int seq = bid >> 3;
  int bh  = xcd * 2 + (seq & 1);
  int q0  = (seq >> 1) * 16;
  int b = bh >> 3, h = bh & 7;
  int wid = threadIdx.x >> 6, lane = threadIdx.x & 63;
  int lr = lane & 15, lg = lane >> 4;
  int col0 = wid * 256;
  // ---- phase 1: QK^T over this wave's 256 keys
  const __bf16* qbase = qh + ((size_t)bh * SDIM + q0) * DH;
  const __bf16* kbase = kh + (size_t)bh * SDIM * DH;
  bf16x8 qf0 = *(const bf16x8*)(qbase + lr * DH + lg * 8);
  bf16x8 qf1 = *(const bf16x8*)(qbase + lr * DH + 32 + lg * 8);
  f32x4 acc[16];
#pragma unroll
  for (int c = 0; c < 16; ++c) {
    const __bf16* kp = kbase + (size_t)(col0 + c * 16 + lr) * DH + lg * 8;
    bf16x8 k0 = *(const bf16x8*)kp;
    bf16x8 k1 = *(const bf16x8*)(kp + 32);
    f32x4 t = {};
    t = mf<C1>(k0, qf0, t);   // row side = K (keys), col side = Q
    t = mf<C1>(k1, qf1, t);
    acc[c] = t;
  }
  // ---- phase 2: blend + mask (permuted bf16 covm, inline) + wave max, exp/sum
  float blend = lam[h] / (lam[h] + 1.f);
  const __bf16* crow = covm + ((size_t)b * SDIM + q0 + lr) * SDIM + col0 + lg * 64;
  float mx = -3.4e38f;
#pragma unroll
  for (int cc = 0; cc < 8; ++cc) {
    bf16x8 cv = *(const bf16x8*)(crow + cc * 8);
#pragma unroll
    for (int j = 0; j < 8; ++j) {
      int c = cc * 2 + (j >> 2);
      int r = j & 3;
      float cf = (float)cv[j];
      float valv = acc[c][r] + blend * cf;
      valv = (cf < -1e30f) ? -1e9f : valv;
      acc[c][r] = valv;
      mx = fmaxf(mx, valv);
    }
  }
  mx = fmaxf(mx, __shfl_xor(mx, 16));
  mx = fmaxf(mx, __shfl_xor(mx, 32));   // wave max for q=lr
  float sm = 0.f;
#pragma unroll
  for (int c = 0; c < 16; ++c) {
#pragma unroll
    for (int r = 0; r < 4; ++r) {
      float p = __expf(acc[c][r] - mx);
      acc[c][r] = p;                     // acc holds exp(S - m_w) <= 1
      sm += p;
    }
  }
  sm += __shfl_xor(sm, 16);
  sm += __shfl_xor(sm, 32);
  if (lg == 0) {
    wredm[wid * 16 + lr] = mx;
    wreds[wid * 16 + lr] = sm;
  }
  __syncthreads();
  // ---- phase 3: combine; sc = e^{m_w - M} / denom (uniform per lane; q = lr)
  float M = wredm[lr];
#pragma unroll
  for (int w = 1; w < 8; ++w) M = fmaxf(M, wredm[w * 16 + lr]);
  float denom = 0.f;
#pragma unroll
  for (int w = 0; w < 8; ++w) denom += wreds[w * 16 + lr] * __expf(wredm[w * 16 + lr] - M);
  float sc = __expf(mx - M) / denom;
  // ---- phase 4: interleaved pack+shuffle+PV + attn stores (spread write burst)
  const __bf16* vbase = vT + (size_t)bh * DH * SDIM + col0;
  float* abase = attn + ((size_t)bh * SDIM + q0 + lr) * SDIM + col0 + lg * 4;
  int src0 = lr + 32 * (lg & 1);
  int src1 = src0 + 16;
  bool hi = (lg & 2) != 0;
  f32x4 oacc[4] = {};
#pragma unroll
  for (int t = 0; t < 8; ++t) {
    unsigned p0 = pack_bf16(acc[t * 2][0], acc[t * 2][1]);
    unsigned p1 = pack_bf16(acc[t * 2][2], acc[t * 2][3]);
    unsigned p2 = pack_bf16(acc[t * 2 + 1][0], acc[t * 2 + 1][1]);
    unsigned p3 = pack_bf16(acc[t * 2 + 1][2], acc[t * 2 + 1][3]);
    // attn stores for chunks 2t, 2t+1 (pre-barrier, disjoint output, sc known)
    {
      f32x4 pn0, pn1;
#pragma unroll
      for (int r = 0; r < 4; ++r) {
        pn0[r] = acc[t * 2][r] * sc;
        pn1[r] = acc[t * 2 + 1][r] * sc;
      }
      *(f32x4*)(abase + (t * 2) * 16) = pn0;
      *(f32x4*)(abase + (t * 2 + 1) * 16) = pn1;
    }
    unsigned a0 = (unsigned)__shfl((int)p0, src0);
    unsigned a1 = (unsigned)__shfl((int)p1, src0);
    unsigned b0 = (unsigned)__shfl((int)p2, src0);
    unsigned b1 = (unsigned)__shfl((int)p3, src0);
    unsigned a2 = (unsigned)__shfl((int)p0, src1);
    unsigned a3 = (unsigned)__shfl((int)p1, src1);
    unsigned b2 = (unsigned)__shfl((int)p2, src1);
    unsigned b3 = (unsigned)__shfl((int)p3, src1);
    u32x4 wv;
    wv[0] = hi ? b0 : a0;
    wv[1] = hi ? b1 : a1;
    wv[2] = hi ? b2 : a2;
    wv[3] = hi ? b3 : a3;
    bf16x8 pfrag = __builtin_bit_cast(bf16x8, wv);
#pragma unroll
    for (int cp = 0; cp < 4; ++cp) {
      bf16x8 vfrag = *(const bf16x8*)(vbase + (size_t)(cp * 16 + lr) * SDIM + t * 32 + lg * 8);
      oacc[cp] = mf<C1>(vfrag, pfrag, oacc[cp]);   // row = dv, col = q (=lr)
    }
  }
  // ---- phase 5: O partials (scaled by own-wave sc) to LDS
#pragma unroll
  for (int cp = 0; cp < 4; ++cp)
#pragma unroll
    for (int rp = 0; rp < 4; ++rp)
      part[(wid * 64 + cp * 16 + lg * 4 + rp) * 17 + lr] = oacc[cp][rp] * sc;
  __syncthreads();
  // ---- phase 6 (post-barrier): oh reduce/store
  {
    int qq = threadIdx.x >> 5;          // 0..15
    int dv = (threadIdx.x & 31) * 2;    // 0,2,..,62
    float s0 = 0.f, s1 = 0.f;
#pragma unroll
    for (int w = 0; w < 8; ++w) {
      s0 += part[(w * 64 + dv) * 17 + qq];
      s1 += part[(w * 64 + dv + 1) * 17 + qq];
    }
    unsigned ow = pack_bf16(s0, s1);
    *(unsigned*)(oh + ((size_t)(b * SDIM + q0 + qq)) * DDIM + h * DH + dv) = ow;
  }
}

__global__ __launch_bounds__(512, 4) void fused_kernel_cov(const __bf16* __restrict__ qh,
                                                           const __bf16* __restrict__ kh,
                                                           const __bf16* __restrict__ vT,
                                                           const __bf16* __restrict__ covm,
                                                           const float* __restrict__ lam,
                                                           float* __restrict__ attn,
                                                           __bf16* __restrict__ oh,
                                                           const int* __restrict__ flag) {
  extern __shared__ float smem[];
  if (*flag == 1) fused_body<true>(qh, kh, vT, covm, lam, attn, oh, smem);
  else            fused_body<false>(qh, kh, vT, covm, lam, attn, oh, smem);
}

// ---- FC + residual: out = oh @ w_fc + q  (f32 out)
template <bool C1>
static __device__ __forceinline__ void fc_body(const __bf16* __restrict__ oh,
                                               const __bf16* __restrict__ wfcT,
                                               const float* __restrict__ resid,
                                               float* __restrict__ out) {
  int n0 = blockIdx.x * 64;
  int m0 = blockIdx.y * 64;
  int wid = threadIdx.x >> 6, lane = threadIdx.x & 63;
  int lr = lane & 15, lg = lane >> 4;
  int mrow = m0 + wid * 16;
  f32x4 acc[4] = {};
  for (int kb = 0; kb < DDIM; kb += 32) {
    bf16x8 afrag = *(const bf16x8*)(oh + (size_t)(mrow + lr) * DDIM + kb + lg * 8);
#pragma unroll
    for (int c = 0; c < 4; ++c) {
      bf16x8 bfrag = *(const bf16x8*)(wfcT + (size_t)(n0 + c * 16 + lr) * DDIM + kb + lg * 8);
      acc[c] = mf<C1>(afrag, bfrag, acc[c]);
    }
  }
#pragma unroll
  for (int c = 0; c < 4; ++c)
#pragma unroll
    for (int r = 0; r < 4; ++r) {
      size_t m = mrow + lg * 4 + r;
      size_t n = n0 + c * 16 + lr;
      out[m * DDIM + n] = acc[c][r] + resid[m * DDIM + n];
    }
}

__global__ __launch_bounds__(256) void fc_kernel(const __bf16* __restrict__ oh,
                                                 const __bf16* __restrict__ wfcT,
                                                 const float* __restrict__ resid,
                                                 float* __restrict__ out,
                                                 const int* __restrict__ flag) {
  if (*flag == 1) fc_body<true>(oh, wfcT, resid, out);
  else            fc_body<false>(oh, wfcT, resid, out);
}

extern "C" void kernel_launch(void* const* d_in, const int* in_sizes, int n_in,
                              void* d_out, int out_size, void* d_ws, size_t ws_size,
                              hipStream_t stream) {
  const float* q = (const float*)d_in[0];
  const float* k = (const float*)d_in[1];
  const float* v = (const float*)d_in[2];
  const float* static_cov = (const float*)d_in[3];
  const int* mask = (const int*)d_in[4];
  const float* w_q = (const float*)d_in[5];
  const float* w_k = (const float*)d_in[6];
  const float* w_v = (const float*)d_in[7];
  const float* w_fc = (const float*)d_in[8];
  const float* lam = (const float*)d_in[9];
  const float* gamma = (const float*)d_in[10];
  const float* beta = (const float*)d_in[11];

  float* out = (float*)d_out;
  float* attn = out + (size_t)2 * SDIM * DDIM;

  char* ws = (char*)d_ws;
  const size_t MB4 = (size_t)4 << 20;
  __bf16* qn  = (__bf16*)(ws);
  __bf16* qh  = (__bf16*)(ws + 1 * MB4);
  __bf16* kh  = (__bf16*)(ws + 2 * MB4);
  __bf16* vT  = (__bf16*)(ws + 3 * MB4);
  __bf16* oh  = (__bf16*)(ws + 4 * MB4);
  __bf16* wqT = (__bf16*)(ws + 5 * MB4);
  __bf16* wkT = (__bf16*)(ws + 5 * MB4 + 524288);
  __bf16* wvT = (__bf16*)(ws + 5 * MB4 + 2 * 524288);
  __bf16* wfcT= (__bf16*)(ws + 5 * MB4 + 3 * 524288);
  int* flag   = (int*)(ws + 5 * MB4 + 4 * 524288);
  __bf16* covm = (__bf16*)(ws + 6 * MB4);   // 16 MiB bf16, ends at 52 MiB

  const unsigned fused_smem = (8 * 64 * 17 + 128 + 128) * 4;   // 35,840 B
  const unsigned proj_smem  = 64 * 72 * 2;                     // 9,216 B

  stageA_kernel<<<dim3(9472), dim3(256), 0, stream>>>(static_cov, mask, covm,
                                                      q, gamma, beta, qn,
                                                      w_q, w_k, w_v, w_fc,
                                                      wqT, wkT, wvT, wfcT, flag);
  proj_kernel<<<dim3(64, 3), dim3(256), proj_smem, stream>>>(qn, k, v, wqT, wkT, wvT, lam, qh, kh, vT, flag);
  fused_kernel_cov<<<dim3(2048), dim3(512), fused_smem, stream>>>(qh, kh, vT, covm, lam, attn, oh, flag);
  fc_kernel<<<dim3(8, 64), dim3(256), 0, stream>>>(oh, wfcT, q, out, flag);
}

// Round 20
// 263.243 us; speedup vs baseline: 1.0696x; 1.0696x over previous
//
#include <hip/hip_runtime.h>
#include <hip/hip_bf16.h>

typedef __attribute__((ext_vector_type(4))) float f32x4;
typedef __attribute__((ext_vector_type(4))) int i32x4;
typedef __attribute__((ext_vector_type(4))) unsigned int u32x4;
typedef __attribute__((ext_vector_type(8))) __bf16 bf16x8;
typedef __attribute__((ext_vector_type(4))) __bf16 bf16x4;

#define SDIM 2048
#define DDIM 512
#define HH 8
#define DH 64

static __device__ __forceinline__ f32x4 mfma_raw(bf16x8 a, bf16x8 b, f32x4 c) {
  return __builtin_amdgcn_mfma_f32_16x16x32_bf16(a, b, c, 0, 0, 0);
}

// Operand-order-corrected MFMA: acc[c][r] = D[row = tile + lg*4 + r][col = lr],
// row side fed by FIRST logical operand under either hardware convention.
template <bool C1>
static __device__ __forceinline__ f32x4 mf(bf16x8 a, bf16x8 b, f32x4 c) {
  return C1 ? mfma_raw(a, b, c) : mfma_raw(b, a, c);
}

static __device__ __forceinline__ unsigned pack_bf16(float a, float b) {
  __bf16 x = (__bf16)a, y = (__bf16)b;
  unsigned short ux = __builtin_bit_cast(unsigned short, x);
  unsigned short uy = __builtin_bit_cast(unsigned short, y);
  return ((unsigned)uy << 16) | (unsigned)ux;
}

// ---- stage A: covm fold -> bf16, lane-permuted (blocks 0..8191) + LayerNorm (8192..9215)
//      + wtrans (9216..9471). Permutation within each 256-key chunk:
//      orig o = c*16 + lg*4 + r  ->  new o = lg*64 + c*4 + r   (c=o>>4, lg=(o>>2)&3)
__global__ __launch_bounds__(256) void stageA_kernel(const float* __restrict__ cov,
                                                     const int* __restrict__ mask,
                                                     __bf16* __restrict__ covm,
                                                     const float* __restrict__ q,
                                                     const float* __restrict__ gamma,
                                                     const float* __restrict__ beta,
                                                     __bf16* __restrict__ qn,
                                                     const float* __restrict__ w0,
                                                     const float* __restrict__ w1,
                                                     const float* __restrict__ w2,
                                                     const float* __restrict__ w3,
                                                     __bf16* __restrict__ t0,
                                                     __bf16* __restrict__ t1,
                                                     __bf16* __restrict__ t2,
                                                     __bf16* __restrict__ t3,
                                                     int* __restrict__ flag) {
  __shared__ float tile[64][65];
  int bid = blockIdx.x;
  if (bid < 8192) {
    size_t i = ((size_t)bid * 256 + threadIdx.x) * 4;
    f32x4 c = *(const f32x4*)(cov + i);
    i32x4 m = *(const i32x4*)(mask + i);
    unsigned o = (unsigned)(i & 255);       // aligned-4, so r component is 0
    unsigned c16 = o >> 4;
    unsigned lgp = (o >> 2) & 3;
    size_t dst = (i & ~(size_t)255) + lgp * 64 + c16 * 4;
    bf16x4 ob;
#pragma unroll
    for (int r = 0; r < 4; ++r) ob[r] = (__bf16)((m[r] == 0) ? -1e38f : c[r]);
    *(bf16x4*)(covm + dst) = ob;
    return;
  }
  if (bid < 9216) {
    int lb = bid - 8192;
    if (lb == 0 && threadIdx.x < 64) {
      float av = (float)(threadIdx.x & 15);
      float bv = av * av;
      bf16x8 a, b;
#pragma unroll
      for (int i = 0; i < 8; ++i) { a[i] = (__bf16)av; b[i] = (__bf16)bv; }
      f32x4 d = {};
      d = mfma_raw(a, b, d);
      if (threadIdx.x == 17) *flag = (d[0] == 128.0f) ? 1 : 2;
    }
    int row = lb * 4 + (threadIdx.x >> 6);
    int lane = threadIdx.x & 63;
    const float* qr = q + (size_t)row * DDIM + lane * 8;
    f32x4 x0 = *(const f32x4*)qr;
    f32x4 x1 = *(const f32x4*)(qr + 4);
    float s = 0.f;
#pragma unroll
    for (int i = 0; i < 4; ++i) s += x0[i] + x1[i];
#pragma unroll
    for (int off = 32; off; off >>= 1) s += __shfl_xor(s, off);
    float mu = s * (1.f / DDIM);
    float vs = 0.f;
#pragma unroll
    for (int i = 0; i < 4; ++i) {
      float d0 = x0[i] - mu, d1 = x1[i] - mu;
      vs += d0 * d0 + d1 * d1;
    }
#pragma unroll
    for (int off = 32; off; off >>= 1) vs += __shfl_xor(vs, off);
    float inv = rsqrtf(vs * (1.f / DDIM) + 1e-6f);
    const float* g = gamma + lane * 8;
    const float* be = beta + lane * 8;
    bf16x8 o;
#pragma unroll
    for (int i = 0; i < 8; ++i) {
      float xv = (i < 4) ? x0[i] : x1[i - 4];
      o[i] = (__bf16)((xv - mu) * inv * g[i] + be[i]);
    }
    *(bf16x8*)(qn + (size_t)row * DDIM + lane * 8) = o;
    return;
  }
  int wb = bid - 9216;
  int which = wb >> 6;
  int rem = wb & 63;
  int n0 = (rem & 7) * 64;
  int k0 = (rem >> 3) * 64;
  const float* w = which == 0 ? w0 : which == 1 ? w1 : which == 2 ? w2 : w3;
  __bf16* t = which == 0 ? t0 : which == 1 ? t1 : which == 2 ? t2 : t3;
  int tx = threadIdx.x & 63, ty = threadIdx.x >> 6;
#pragma unroll
  for (int j = 0; j < 16; ++j) {
    int kk = ty * 16 + j;
    tile[kk][tx] = w[(size_t)(k0 + kk) * DDIM + n0 + tx];
  }
  __syncthreads();
#pragma unroll
  for (int j = 0; j < 16; ++j) {
    int n = ty * 16 + j;
    t[(size_t)(n0 + n) * DDIM + k0 + tx] = (__bf16)tile[tx][n];
  }
}

// ---- projections v3: each block computes 64 rows x 2 heads (128 cols).
// A fragments cached in registers (A read 4x instead of 8x); grid (64,4,3) = 768 blocks.
template <bool C1>
static __device__ __forceinline__ void proj_body(const __bf16* __restrict__ qn,
                                                 const float* __restrict__ kin,
                                                 const float* __restrict__ vin,
                                                 const __bf16* __restrict__ wqT,
                                                 const __bf16* __restrict__ wkT,
                                                 const __bf16* __restrict__ wvT,
                                                 const float* __restrict__ lam,
                                                 __bf16* __restrict__ qh,
                                                 __bf16* __restrict__ kh,
                                                 __bf16* __restrict__ vT,
                                                 __bf16* __restrict__ tr) {
  int which = blockIdx.z;
  int m0 = blockIdx.x * 64;
  int h0 = blockIdx.y * 2;
  int wid = threadIdx.x >> 6, lane = threadIdx.x & 63;
  int lr = lane & 15, lg = lane >> 4;
  int mrow = m0 + wid * 16;
  const __bf16* wT = which == 0 ? wqT : which == 1 ? wkT : wvT;
  // cache A fragments: row mrow+lr, k = kb*32 + lg*8 .. +8  (64 VGPRs)
  bf16x8 af[16];
  if (which == 0) {
#pragma unroll
    for (int kb = 0; kb < 16; ++kb)
      af[kb] = *(const bf16x8*)(qn + (size_t)(mrow + lr) * DDIM + kb * 32 + lg * 8);
  } else {
    const float* A = which == 1 ? kin : vin;
#pragma unroll
    for (int kb = 0; kb < 16; ++kb) {
      const float* src = A + (size_t)(mrow + lr) * DDIM + kb * 32 + lg * 8;
      f32x4 y0 = *(const f32x4*)src;
      f32x4 y1 = *(const f32x4*)(src + 4);
      bf16x8 a;
#pragma unroll
      for (int i = 0; i < 4; ++i) { a[i] = (__bf16)y0[i]; a[i + 4] = (__bf16)y1[i]; }
      af[kb] = a;
    }
  }
  int bq = m0 >> 11;
  int ss0 = m0 & 2047;
#pragma unroll
  for (int hh = 0; hh < 2; ++hh) {
    int h = h0 + hh;
    int n0 = h * 64;
    f32x4 acc[4] = {};
#pragma unroll
    for (int kb = 0; kb < 16; ++kb) {
#pragma unroll
      for (int c = 0; c < 4; ++c) {
        bf16x8 bfrag = *(const bf16x8*)(wT + (size_t)(n0 + c * 16 + lr) * DDIM + kb * 32 + lg * 8);
        acc[c] = mf<C1>(af[kb], bfrag, acc[c]);
      }
    }
    // stage into LDS: qk path -> [m_local][dd]; v path -> [dd][m_local]; stride 72
    if (which == 0) {
      float sc = 1.f / (8.f * (lam[h] + 1.f));
#pragma unroll
      for (int c = 0; c < 4; ++c)
#pragma unroll
        for (int r = 0; r < 4; ++r)
          tr[(wid * 16 + lg * 4 + r) * 72 + c * 16 + lr] = (__bf16)(acc[c][r] * sc);
    } else if (which == 1) {
#pragma unroll
      for (int c = 0; c < 4; ++c)
#pragma unroll
        for (int r = 0; r < 4; ++r)
          tr[(wid * 16 + lg * 4 + r) * 72 + c * 16 + lr] = (__bf16)acc[c][r];
    } else {
#pragma unroll
      for (int c = 0; c < 4; ++c)
#pragma unroll
        for (int r = 0; r < 4; ++r)
          tr[(c * 16 + lr) * 72 + wid * 16 + lg * 4 + r] = (__bf16)acc[c][r];
    }
    __syncthreads();
    size_t bh2 = (size_t)bq * HH + h;
#pragma unroll
    for (int ii = 0; ii < 2; ++ii) {
      int row = (threadIdx.x >> 3) + ii * 32;
      int col = (threadIdx.x & 7) * 8;
      bf16x8 v8 = *(const bf16x8*)(tr + row * 72 + col);
      if (which == 2) {
        *(bf16x8*)(vT + (bh2 * DH + row) * SDIM + ss0 + col) = v8;
      } else {
        __bf16* dst = (which == 0 ? qh : kh);
        *(bf16x8*)(dst + (bh2 * SDIM + ss0 + row) * DH + col) = v8;
      }
    }
    if (hh == 0) __syncthreads();   // tr reused for second head
  }
}

__global__ __launch_bounds__(256, 2) void proj_kernel(const __bf16* __restrict__ qn,
                                                      const float* __restrict__ kin,
                                                      const float* __restrict__ vin,
                                                      const __bf16* __restrict__ wqT,
                                                      const __bf16* __restrict__ wkT,
                                                      const __bf16* __restrict__ wvT,
                                                      const float* __restrict__ lam,
                                                      __bf16* __restrict__ qh,
                                                      __bf16* __restrict__ kh,
                                                      __bf16* __restrict__ vT,
                                                      const int* __restrict__ flag) {
  extern __shared__ __bf16 psm[];   // [64][72]
  if (*flag == 1) proj_body<true>(qn, kin, vin, wqT, wkT, wvT, lam, qh, kh, vT, psm);
  else            proj_body<false>(qn, kin, vin, wqT, wkT, wvT, lam, qh, kh, vT, psm);
}

// ---- FUSED: 512 thr (8 waves), KPW=256, 2 blocks/CU, 2 barriers. (r17 config)
// bf16 lane-permuted covm loaded inline in phase 2; attn stores interleaved into phase 4.
template <bool C1>
static __device__ __forceinline__ void fused_body(const __bf16* __restrict__ qh,
                                                  const __bf16* __restrict__ kh,
                                                  const __bf16* __restrict__ vT,
                                                  const __bf16* __restrict__ covm,
                                                  const float* __restrict__ lam,
                                                  float* __restrict__ attn,
                                                  __bf16* __restrict__ oh,
                                                  float* __restrict__ smem) {
  float* part  = smem;                   // [8][64] stride 17
  float* wredm = smem + 8 * 64 * 17;     // [8][16] wave max
  float* wreds = wredm + 128;            // [8][16] wave sum
  int bid = blockIdx.x;
  int xcd = bid & 7;
  int seq = bid >> 3;
  int bh  = xcd * 2 + (seq & 1);
  int q0  = (seq >> 1) * 16;
  int b = bh >> 3, h = bh & 7;
  int wid = threadIdx.x >> 6, lane = threadIdx.x & 63;
  int lr = lane & 15, lg = lane >> 4;
  int col0 = wid * 256;
  // ---- phase 1: QK^T over this wave's 256 keys
  const __bf16* qbase = qh + ((size_t)bh * SDIM + q0) * DH;
  const __bf16* kbase = kh + (size_t)bh * SDIM * DH;
  bf16x8 qf0 = *(const bf16x8*)(qbase + lr * DH + lg * 8);
  bf16x8 qf1 = *(const bf16x8*)(qbase + lr * DH + 32 + lg * 8);
  f32x4 acc[16];
#pragma unroll
  for (int c = 0; c < 16; ++c) {
    const __bf16* kp = kbase + (size_t)(col0 + c * 16 + lr) * DH + lg * 8;
    bf16x8 k0 = *(const bf16x8*)kp;
    bf16x8 k1 = *(const bf16x8*)(kp + 32);
    f32x4 t = {};
    t = mf<C1>(k0, qf0, t);   // row side = K (keys), col side = Q
    t = mf<C1>(k1, qf1, t);
    acc[c] = t;
  }
  // ---- phase 2: blend + mask (permuted bf16 covm, inline) + wave max, exp/sum
  float blend = lam[h] / (lam[h] + 1.f);
  const __bf16* crow = covm + ((size_t)b * SDIM + q0 + lr) * SDIM + col0 + lg * 64;
  float mx = -3.4e38f;
#pragma unroll
  for (int cc = 0; cc < 8; ++cc) {
    bf16x8 cv = *(const bf16x8*)(crow + cc * 8);
#pragma unroll
    for (int j = 0; j < 8; ++j) {
      int c = cc * 2 + (j >> 2);
      int r = j & 3;
      float cf = (float)cv[j];
      float valv = acc[c][r] + blend * cf;
      valv = (cf < -1e30f) ? -1e9f : valv;
      acc[c][r] = valv;
      mx = fmaxf(mx, valv);
    }
  }
  mx = fmaxf(mx, __shfl_xor(mx, 16));
  mx = fmaxf(mx, __shfl_xor(mx, 32));   // wave max for q=lr
  float sm = 0.f;
#pragma unroll
  for (int c = 0; c < 16; ++c) {
#pragma unroll
    for (int r = 0; r < 4; ++r) {
      float p = __expf(acc[c][r] - mx);
      acc[c][r] = p;                     // acc holds exp(S - m_w) <= 1
      sm += p;
    }
  }
  sm += __shfl_xor(sm, 16);
  sm += __shfl_xor(sm, 32);
  if (lg == 0) {
    wredm[wid * 16 + lr] = mx;
    wreds[wid * 16 + lr] = sm;
  }
  __syncthreads();
  // ---- phase 3: combine; sc = e^{m_w - M} / denom (uniform per lane; q = lr)
  float M = wredm[lr];
#pragma unroll
  for (int w = 1; w < 8; ++w) M = fmaxf(M, wredm[w * 16 + lr]);
  float denom = 0.f;
#pragma unroll
  for (int w = 0; w < 8; ++w) denom += wreds[w * 16 + lr] * __expf(wredm[w * 16 + lr] - M);
  float sc = __expf(mx - M) / denom;
  // ---- phase 4: interleaved pack+shuffle+PV + attn stores (spread write burst)
  const __bf16* vbase = vT + (size_t)bh * DH * SDIM + col0;
  float* abase = attn + ((size_t)bh * SDIM + q0 + lr) * SDIM + col0 + lg * 4;
  int src0 = lr + 32 * (lg & 1);
  int src1 = src0 + 16;
  bool hi = (lg & 2) != 0;
  f32x4 oacc[4] = {};
#pragma unroll
  for (int t = 0; t < 8; ++t) {
    unsigned p0 = pack_bf16(acc[t * 2][0], acc[t * 2][1]);
    unsigned p1 = pack_bf16(acc[t * 2][2], acc[t * 2][3]);
    unsigned p2 = pack_bf16(acc[t * 2 + 1][0], acc[t * 2 + 1][1]);
    unsigned p3 = pack_bf16(acc[t * 2 + 1][2], acc[t * 2 + 1][3]);
    // attn stores for chunks 2t, 2t+1 (pre-barrier, disjoint output, sc known)
    {
      f32x4 pn0, pn1;
#pragma unroll
      for (int r = 0; r < 4; ++r) {
        pn0[r] = acc[t * 2][r] * sc;
        pn1[r] = acc[t * 2 + 1][r] * sc;
      }
      *(f32x4*)(abase + (t * 2) * 16) = pn0;
      *(f32x4*)(abase + (t * 2 + 1) * 16) = pn1;
    }
    unsigned a0 = (unsigned)__shfl((int)p0, src0);
    unsigned a1 = (unsigned)__shfl((int)p1, src0);
    unsigned b0 = (unsigned)__shfl((int)p2, src0);
    unsigned b1 = (unsigned)__shfl((int)p3, src0);
    unsigned a2 = (unsigned)__shfl((int)p0, src1);
    unsigned a3 = (unsigned)__shfl((int)p1, src1);
    unsigned b2 = (unsigned)__shfl((int)p2, src1);
    unsigned b3 = (unsigned)__shfl((int)p3, src1);
    u32x4 wv;
    wv[0] = hi ? b0 : a0;
    wv[1] = hi ? b1 : a1;
    wv[2] = hi ? b2 : a2;
    wv[3] = hi ? b3 : a3;
    bf16x8 pfrag = __builtin_bit_cast(bf16x8, wv);
#pragma unroll
    for (int cp = 0; cp < 4; ++cp) {
      bf16x8 vfrag = *(const bf16x8*)(vbase + (size_t)(cp * 16 + lr) * SDIM + t * 32 + lg * 8);
      oacc[cp] = mf<C1>(vfrag, pfrag, oacc[cp]);   // row = dv, col = q (=lr)
    }
  }
  // ---- phase 5: O partials (scaled by own-wave sc) to LDS
#pragma unroll
  for (int cp = 0; cp < 4; ++cp)
#pragma unroll
    for (int rp = 0; rp < 4; ++rp)
      part[(wid * 64 + cp * 16 + lg * 4 + rp) * 17 + lr] = oacc[cp][rp] * sc;
  __syncthreads();
  // ---- phase 6 (post-barrier): oh reduce/store
  {
    int qq = threadIdx.x >> 5;          // 0..15
    int dv = (threadIdx.x & 31) * 2;    // 0,2,..,62
    float s0 = 0.f, s1 = 0.f;
#pragma unroll
    for (int w = 0; w < 8; ++w) {
      s0 += part[(w * 64 + dv) * 17 + qq];
      s1 += part[(w * 64 + dv + 1) * 17 + qq];
    }
    unsigned ow = pack_bf16(s0, s1);
    *(unsigned*)(oh + ((size_t)(b * SDIM + q0 + qq)) * DDIM + h * DH + dv) = ow;
  }
}

__global__ __launch_bounds__(512, 4) void fused_kernel_cov(const __bf16* __restrict__ qh,
                                                           const __bf16* __restrict__ kh,
                                                           const __bf16* __restrict__ vT,
                                                           const __bf16* __restrict__ covm,
                                                           const float* __restrict__ lam,
                                                           float* __restrict__ attn,
                                                           __bf16* __restrict__ oh,
                                                           const int* __restrict__ flag) {
  extern __shared__ float smem[];
  if (*flag == 1) fused_body<true>(qh, kh, vT, covm, lam, attn, oh, smem);
  else            fused_body<false>(qh, kh, vT, covm, lam, attn, oh, smem);
}

// ---- FC + residual: out = oh @ w_fc + q  (f32 out)
template <bool C1>
static __device__ __forceinline__ void fc_body(const __bf16* __restrict__ oh,
                                               const __bf16* __restrict__ wfcT,
                                               const float* __restrict__ resid,
                                               float* __restrict__ out) {
  int n0 = blockIdx.x * 64;
  int m0 = blockIdx.y * 64;
  int wid = threadIdx.x >> 6, lane = threadIdx.x & 63;
  int lr = lane & 15, lg = lane >> 4;
  int mrow = m0 + wid * 16;
  f32x4 acc[4] = {};
  for (int kb = 0; kb < DDIM; kb += 32) {
    bf16x8 afrag = *(const bf16x8*)(oh + (size_t)(mrow + lr) * DDIM + kb + lg * 8);
#pragma unroll
    for (int c = 0; c < 4; ++c) {
      bf16x8 bfrag = *(const bf16x8*)(wfcT + (size_t)(n0 + c * 16 + lr) * DDIM + kb + lg * 8);
      acc[c] = mf<C1>(afrag, bfrag, acc[c]);
    }
  }
#pragma unroll
  for (int c = 0; c < 4; ++c)
#pragma unroll
    for (int r = 0; r < 4; ++r) {
      size_t m = mrow + lg * 4 + r;
      size_t n = n0 + c * 16 + lr;
      out[m * DDIM + n] = acc[c][r] + resid[m * DDIM + n];
    }
}

__global__ __launch_bounds__(256) void fc_kernel(const __bf16* __restrict__ oh,
                                                 const __bf16* __restrict__ wfcT,
                                                 const float* __restrict__ resid,
                                                 float* __restrict__ out,
                                                 const int* __restrict__ flag) {
  if (*flag == 1) fc_body<true>(oh, wfcT, resid, out);
  else            fc_body<false>(oh, wfcT, resid, out);
}

extern "C" void kernel_launch(void* const* d_in, const int* in_sizes, int n_in,
                              void* d_out, int out_size, void* d_ws, size_t ws_size,
                              hipStream_t stream) {
  const float* q = (const float*)d_in[0];
  const float* k = (const float*)d_in[1];
  const float* v = (const float*)d_in[2];
  const float* static_cov = (const float*)d_in[3];
  const int* mask = (const int*)d_in[4];
  const float* w_q = (const float*)d_in[5];
  const float* w_k = (const float*)d_in[6];
  const float* w_v = (const float*)d_in[7];
  const float* w_fc = (const float*)d_in[8];
  const float* lam = (const float*)d_in[9];
  const float* gamma = (const float*)d_in[10];
  const float* beta = (const float*)d_in[11];

  float* out = (float*)d_out;
  float* attn = out + (size_t)2 * SDIM * DDIM;

  char* ws = (char*)d_ws;
  const size_t MB4 = (size_t)4 << 20;
  __bf16* qn  = (__bf16*)(ws);
  __bf16* qh  = (__bf16*)(ws + 1 * MB4);
  __bf16* kh  = (__bf16*)(ws + 2 * MB4);
  __bf16* vT  = (__bf16*)(ws + 3 * MB4);
  __bf16* oh  = (__bf16*)(ws + 4 * MB4);
  __bf16* wqT = (__bf16*)(ws + 5 * MB4);
  __bf16* wkT = (__bf16*)(ws + 5 * MB4 + 524288);
  __bf16* wvT = (__bf16*)(ws + 5 * MB4 + 2 * 524288);
  __bf16* wfcT= (__bf16*)(ws + 5 * MB4 + 3 * 524288);
  int* flag   = (int*)(ws + 5 * MB4 + 4 * 524288);
  __bf16* covm = (__bf16*)(ws + 6 * MB4);   // 16 MiB bf16, ends at 52 MiB

  const unsigned fused_smem = (8 * 64 * 17 + 128 + 128) * 4;   // 35,840 B
  const unsigned proj_smem  = 64 * 72 * 2;                     // 9,216 B

  stageA_kernel<<<dim3(9472), dim3(256), 0, stream>>>(static_cov, mask, covm,
                                                      q, gamma, beta, qn,
                                                      w_q, w_k, w_v, w_fc,
                                                      wqT, wkT, wvT, wfcT, flag);
  proj_kernel<<<dim3(64, 4, 3), dim3(256), proj_smem, stream>>>(qn, k, v, wqT, wkT, wvT, lam, qh, kh, vT, flag);
  fused_kernel_cov<<<dim3(2048), dim3(512), fused_smem, stream>>>(qh, kh, vT, covm, lam, attn, oh, flag);
  fc_kernel<<<dim3(8, 64), dim3(256), 0, stream>>>(oh, wfcT, q, out, flag);
}

// Round 21
// 258.947 us; speedup vs baseline: 1.0874x; 1.0166x over previous
//
#include <hip/hip_runtime.h>
#include <hip/hip_bf16.h>

typedef __attribute__((ext_vector_type(4))) float f32x4;
typedef __attribute__((ext_vector_type(4))) int i32x4;
typedef __attribute__((ext_vector_type(4))) unsigned int u32x4;
typedef __attribute__((ext_vector_type(8))) __bf16 bf16x8;
typedef __attribute__((ext_vector_type(4))) __bf16 bf16x4;

#define SDIM 2048
#define DDIM 512
#define HH 8
#define DH 64

static __device__ __forceinline__ f32x4 mfma_raw(bf16x8 a, bf16x8 b, f32x4 c) {
  return __builtin_amdgcn_mfma_f32_16x16x32_bf16(a, b, c, 0, 0, 0);
}

// Operand-order-corrected MFMA: acc[c][r] = D[row = tile + lg*4 + r][col = lr],
// row side fed by FIRST logical operand under either hardware convention.
template <bool C1>
static __device__ __forceinline__ f32x4 mf(bf16x8 a, bf16x8 b, f32x4 c) {
  return C1 ? mfma_raw(a, b, c) : mfma_raw(b, a, c);
}

static __device__ __forceinline__ unsigned pack_bf16(float a, float b) {
  __bf16 x = (__bf16)a, y = (__bf16)b;
  unsigned short ux = __builtin_bit_cast(unsigned short, x);
  unsigned short uy = __builtin_bit_cast(unsigned short, y);
  return ((unsigned)uy << 16) | (unsigned)ux;
}

// ---- stage B: LayerNorm (blocks 0..1023, probe in block 0) + wtrans (1024..1279)
__global__ __launch_bounds__(256) void stageB_kernel(const float* __restrict__ q,
                                                     const float* __restrict__ gamma,
                                                     const float* __restrict__ beta,
                                                     __bf16* __restrict__ qn,
                                                     const float* __restrict__ w0,
                                                     const float* __restrict__ w1,
                                                     const float* __restrict__ w2,
                                                     const float* __restrict__ w3,
                                                     __bf16* __restrict__ t0,
                                                     __bf16* __restrict__ t1,
                                                     __bf16* __restrict__ t2,
                                                     __bf16* __restrict__ t3,
                                                     int* __restrict__ flag) {
  __shared__ float tile[64][65];
  int bid = blockIdx.x;
  if (bid < 1024) {
    if (bid == 0 && threadIdx.x < 64) {
      float av = (float)(threadIdx.x & 15);
      float bv = av * av;
      bf16x8 a, b;
#pragma unroll
      for (int i = 0; i < 8; ++i) { a[i] = (__bf16)av; b[i] = (__bf16)bv; }
      f32x4 d = {};
      d = mfma_raw(a, b, d);
      if (threadIdx.x == 17) *flag = (d[0] == 128.0f) ? 1 : 2;
    }
    int row = bid * 4 + (threadIdx.x >> 6);
    int lane = threadIdx.x & 63;
    const float* qr = q + (size_t)row * DDIM + lane * 8;
    f32x4 x0 = *(const f32x4*)qr;
    f32x4 x1 = *(const f32x4*)(qr + 4);
    float s = 0.f;
#pragma unroll
    for (int i = 0; i < 4; ++i) s += x0[i] + x1[i];
#pragma unroll
    for (int off = 32; off; off >>= 1) s += __shfl_xor(s, off);
    float mu = s * (1.f / DDIM);
    float vs = 0.f;
#pragma unroll
    for (int i = 0; i < 4; ++i) {
      float d0 = x0[i] - mu, d1 = x1[i] - mu;
      vs += d0 * d0 + d1 * d1;
    }
#pragma unroll
    for (int off = 32; off; off >>= 1) vs += __shfl_xor(vs, off);
    float inv = rsqrtf(vs * (1.f / DDIM) + 1e-6f);
    const float* g = gamma + lane * 8;
    const float* be = beta + lane * 8;
    bf16x8 o;
#pragma unroll
    for (int i = 0; i < 8; ++i) {
      float xv = (i < 4) ? x0[i] : x1[i - 4];
      o[i] = (__bf16)((xv - mu) * inv * g[i] + be[i]);
    }
    *(bf16x8*)(qn + (size_t)row * DDIM + lane * 8) = o;
    return;
  }
  int wb = bid - 1024;
  int which = wb >> 6;
  int rem = wb & 63;
  int n0 = (rem & 7) * 64;
  int k0 = (rem >> 3) * 64;
  const float* w = which == 0 ? w0 : which == 1 ? w1 : which == 2 ? w2 : w3;
  __bf16* t = which == 0 ? t0 : which == 1 ? t1 : which == 2 ? t2 : t3;
  int tx = threadIdx.x & 63, ty = threadIdx.x >> 6;
#pragma unroll
  for (int j = 0; j < 16; ++j) {
    int kk = ty * 16 + j;
    tile[kk][tx] = w[(size_t)(k0 + kk) * DDIM + n0 + tx];
  }
  __syncthreads();
#pragma unroll
  for (int j = 0; j < 16; ++j) {
    int n = ty * 16 + j;
    t[(size_t)(n0 + n) * DDIM + k0 + tx] = (__bf16)tile[tx][n];
  }
}

// ---- projections v3 + covm fold merged (z==3 blocks do the bf16 lane-permuted fold).
// proj: each block computes 64 rows x 2 heads (128 cols); A cached in registers.
template <bool C1>
static __device__ __forceinline__ void proj_body(const __bf16* __restrict__ qn,
                                                 const float* __restrict__ kin,
                                                 const float* __restrict__ vin,
                                                 const __bf16* __restrict__ wqT,
                                                 const __bf16* __restrict__ wkT,
                                                 const __bf16* __restrict__ wvT,
                                                 const float* __restrict__ lam,
                                                 __bf16* __restrict__ qh,
                                                 __bf16* __restrict__ kh,
                                                 __bf16* __restrict__ vT,
                                                 __bf16* __restrict__ tr) {
  int which = blockIdx.z;
  int m0 = blockIdx.x * 64;
  int h0 = blockIdx.y * 2;
  int wid = threadIdx.x >> 6, lane = threadIdx.x & 63;
  int lr = lane & 15, lg = lane >> 4;
  int mrow = m0 + wid * 16;
  const __bf16* wT = which == 0 ? wqT : which == 1 ? wkT : wvT;
  bf16x8 af[16];
  if (which == 0) {
#pragma unroll
    for (int kb = 0; kb < 16; ++kb)
      af[kb] = *(const bf16x8*)(qn + (size_t)(mrow + lr) * DDIM + kb * 32 + lg * 8);
  } else {
    const float* A = which == 1 ? kin : vin;
#pragma unroll
    for (int kb = 0; kb < 16; ++kb) {
      const float* src = A + (size_t)(mrow + lr) * DDIM + kb * 32 + lg * 8;
      f32x4 y0 = *(const f32x4*)src;
      f32x4 y1 = *(const f32x4*)(src + 4);
      bf16x8 a;
#pragma unroll
      for (int i = 0; i < 4; ++i) { a[i] = (__bf16)y0[i]; a[i + 4] = (__bf16)y1[i]; }
      af[kb] = a;
    }
  }
  int bq = m0 >> 11;
  int ss0 = m0 & 2047;
#pragma unroll
  for (int hh = 0; hh < 2; ++hh) {
    int h = h0 + hh;
    int n0 = h * 64;
    f32x4 acc[4] = {};
#pragma unroll
    for (int kb = 0; kb < 16; ++kb) {
#pragma unroll
      for (int c = 0; c < 4; ++c) {
        bf16x8 bfrag = *(const bf16x8*)(wT + (size_t)(n0 + c * 16 + lr) * DDIM + kb * 32 + lg * 8);
        acc[c] = mf<C1>(af[kb], bfrag, acc[c]);
      }
    }
    if (which == 0) {
      float sc = 1.f / (8.f * (lam[h] + 1.f));
#pragma unroll
      for (int c = 0; c < 4; ++c)
#pragma unroll
        for (int r = 0; r < 4; ++r)
          tr[(wid * 16 + lg * 4 + r) * 72 + c * 16 + lr] = (__bf16)(acc[c][r] * sc);
    } else if (which == 1) {
#pragma unroll
      for (int c = 0; c < 4; ++c)
#pragma unroll
        for (int r = 0; r < 4; ++r)
          tr[(wid * 16 + lg * 4 + r) * 72 + c * 16 + lr] = (__bf16)acc[c][r];
    } else {
#pragma unroll
      for (int c = 0; c < 4; ++c)
#pragma unroll
        for (int r = 0; r < 4; ++r)
          tr[(c * 16 + lr) * 72 + wid * 16 + lg * 4 + r] = (__bf16)acc[c][r];
    }
    __syncthreads();
    size_t bh2 = (size_t)bq * HH + h;
#pragma unroll
    for (int ii = 0; ii < 2; ++ii) {
      int row = (threadIdx.x >> 3) + ii * 32;
      int col = (threadIdx.x & 7) * 8;
      bf16x8 v8 = *(const bf16x8*)(tr + row * 72 + col);
      if (which == 2) {
        *(bf16x8*)(vT + (bh2 * DH + row) * SDIM + ss0 + col) = v8;
      } else {
        __bf16* dst = (which == 0 ? qh : kh);
        *(bf16x8*)(dst + (bh2 * SDIM + ss0 + row) * DH + col) = v8;
      }
    }
    if (hh == 0) __syncthreads();
  }
}

__global__ __launch_bounds__(256, 2) void proj_kernel(const __bf16* __restrict__ qn,
                                                      const float* __restrict__ kin,
                                                      const float* __restrict__ vin,
                                                      const __bf16* __restrict__ wqT,
                                                      const __bf16* __restrict__ wkT,
                                                      const __bf16* __restrict__ wvT,
                                                      const float* __restrict__ lam,
                                                      __bf16* __restrict__ qh,
                                                      __bf16* __restrict__ kh,
                                                      __bf16* __restrict__ vT,
                                                      const float* __restrict__ cov,
                                                      const int* __restrict__ mask,
                                                      __bf16* __restrict__ covm,
                                                      const int* __restrict__ flag) {
  extern __shared__ __bf16 psm[];   // [64][72]
  if (blockIdx.z == 3) {
    // covm fold: covm = bf16(mask ? cov : -1e38), lane-permuted within 256-elem chunks
    int cb = blockIdx.x * 4 + blockIdx.y;   // 0..255
#pragma unroll 4
    for (int it = 0; it < 32; ++it) {
      size_t i = (((size_t)cb * 32 + it) * 256 + threadIdx.x) * 4;
      f32x4 c = *(const f32x4*)(cov + i);
      i32x4 m = *(const i32x4*)(mask + i);
      unsigned o = (unsigned)(i & 255);
      unsigned c16 = o >> 4;
      unsigned lgp = (o >> 2) & 3;
      size_t dst = (i & ~(size_t)255) + lgp * 64 + c16 * 4;
      bf16x4 ob;
#pragma unroll
      for (int r = 0; r < 4; ++r) ob[r] = (__bf16)((m[r] == 0) ? -1e38f : c[r]);
      *(bf16x4*)(covm + dst) = ob;
    }
    return;
  }
  if (*flag == 1) proj_body<true>(qn, kin, vin, wqT, wkT, wvT, lam, qh, kh, vT, psm);
  else            proj_body<false>(qn, kin, vin, wqT, wkT, wvT, lam, qh, kh, vT, psm);
}

// ---- FUSED: 512 thr (8 waves), KPW=256, 2 blocks/CU, 2 barriers. (r17 config, untouched)
template <bool C1>
static __device__ __forceinline__ void fused_body(const __bf16* __restrict__ qh,
                                                  const __bf16* __restrict__ kh,
                                                  const __bf16* __restrict__ vT,
                                                  const __bf16* __restrict__ covm,
                                                  const float* __restrict__ lam,
                                                  float* __restrict__ attn,
                                                  __bf16* __restrict__ oh,
                                                  float* __restrict__ smem) {
  float* part  = smem;                   // [8][64] stride 17
  float* wredm = smem + 8 * 64 * 17;     // [8][16] wave max
  float* wreds = wredm + 128;            // [8][16] wave sum
  int bid = blockIdx.x;
  int xcd = bid & 7;
  int seq = bid >> 3;
  int bh  = xcd * 2 + (seq & 1);
  int q0  = (seq >> 1) * 16;
  int b = bh >> 3, h = bh & 7;
  int wid = threadIdx.x >> 6, lane = threadIdx.x & 63;
  int lr = lane & 15, lg = lane >> 4;
  int col0 = wid * 256;
  const __bf16* qbase = qh + ((size_t)bh * SDIM + q0) * DH;
  const __bf16* kbase = kh + (size_t)bh * SDIM * DH;
  bf16x8 qf0 = *(const bf16x8*)(qbase + lr * DH + lg * 8);
  bf16x8 qf1 = *(const bf16x8*)(qbase + lr * DH + 32 + lg * 8);
  f32x4 acc[16];
#pragma unroll
  for (int c = 0; c < 16; ++c) {
    const __bf16* kp = kbase + (size_t)(col0 + c * 16 + lr) * DH + lg * 8;
    bf16x8 k0 = *(const bf16x8*)kp;
    bf16x8 k1 = *(const bf16x8*)(kp + 32);
    f32x4 t = {};
    t = mf<C1>(k0, qf0, t);   // row side = K (keys), col side = Q
    t = mf<C1>(k1, qf1, t);
    acc[c] = t;
  }
  float blend = lam[h] / (lam[h] + 1.f);
  const __bf16* crow = covm + ((size_t)b * SDIM + q0 + lr) * SDIM + col0 + lg * 64;
  float mx = -3.4e38f;
#pragma unroll
  for (int cc = 0; cc < 8; ++cc) {
    bf16x8 cv = *(const bf16x8*)(crow + cc * 8);
#pragma unroll
    for (int j = 0; j < 8; ++j) {
      int c = cc * 2 + (j >> 2);
      int r = j & 3;
      float cf = (float)cv[j];
      float valv = acc[c][r] + blend * cf;
      valv = (cf < -1e30f) ? -1e9f : valv;
      acc[c][r] = valv;
      mx = fmaxf(mx, valv);
    }
  }
  mx = fmaxf(mx, __shfl_xor(mx, 16));
  mx = fmaxf(mx, __shfl_xor(mx, 32));   // wave max for q=lr
  float sm = 0.f;
#pragma unroll
  for (int c = 0; c < 16; ++c) {
#pragma unroll
    for (int r = 0; r < 4; ++r) {
      float p = __expf(acc[c][r] - mx);
      acc[c][r] = p;                     // acc holds exp(S - m_w) <= 1
      sm += p;
    }
  }
  sm += __shfl_xor(sm, 16);
  sm += __shfl_xor(sm, 32);
  if (lg == 0) {
    wredm[wid * 16 + lr] = mx;
    wreds[wid * 16 + lr] = sm;
  }
  __syncthreads();
  float M = wredm[lr];
#pragma unroll
  for (int w = 1; w < 8; ++w) M = fmaxf(M, wredm[w * 16 + lr]);
  float denom = 0.f;
#pragma unroll
  for (int w = 0; w < 8; ++w) denom += wreds[w * 16 + lr] * __expf(wredm[w * 16 + lr] - M);
  float sc = __expf(mx - M) / denom;
  const __bf16* vbase = vT + (size_t)bh * DH * SDIM + col0;
  float* abase = attn + ((size_t)bh * SDIM + q0 + lr) * SDIM + col0 + lg * 4;
  int src0 = lr + 32 * (lg & 1);
  int src1 = src0 + 16;
  bool hi = (lg & 2) != 0;
  f32x4 oacc[4] = {};
#pragma unroll
  for (int t = 0; t < 8; ++t) {
    unsigned p0 = pack_bf16(acc[t * 2][0], acc[t * 2][1]);
    unsigned p1 = pack_bf16(acc[t * 2][2], acc[t * 2][3]);
    unsigned p2 = pack_bf16(acc[t * 2 + 1][0], acc[t * 2 + 1][1]);
    unsigned p3 = pack_bf16(acc[t * 2 + 1][2], acc[t * 2 + 1][3]);
    {
      f32x4 pn0, pn1;
#pragma unroll
      for (int r = 0; r < 4; ++r) {
        pn0[r] = acc[t * 2][r] * sc;
        pn1[r] = acc[t * 2 + 1][r] * sc;
      }
      *(f32x4*)(abase + (t * 2) * 16) = pn0;
      *(f32x4*)(abase + (t * 2 + 1) * 16) = pn1;
    }
    unsigned a0 = (unsigned)__shfl((int)p0, src0);
    unsigned a1 = (unsigned)__shfl((int)p1, src0);
    unsigned b0 = (unsigned)__shfl((int)p2, src0);
    unsigned b1 = (unsigned)__shfl((int)p3, src0);
    unsigned a2 = (unsigned)__shfl((int)p0, src1);
    unsigned a3 = (unsigned)__shfl((int)p1, src1);
    unsigned b2 = (unsigned)__shfl((int)p2, src1);
    unsigned b3 = (unsigned)__shfl((int)p3, src1);
    u32x4 wv;
    wv[0] = hi ? b0 : a0;
    wv[1] = hi ? b1 : a1;
    wv[2] = hi ? b2 : a2;
    wv[3] = hi ? b3 : a3;
    bf16x8 pfrag = __builtin_bit_cast(bf16x8, wv);
#pragma unroll
    for (int cp = 0; cp < 4; ++cp) {
      bf16x8 vfrag = *(const bf16x8*)(vbase + (size_t)(cp * 16 + lr) * SDIM + t * 32 + lg * 8);
      oacc[cp] = mf<C1>(vfrag, pfrag, oacc[cp]);   // row = dv, col = q (=lr)
    }
  }
#pragma unroll
  for (int cp = 0; cp < 4; ++cp)
#pragma unroll
    for (int rp = 0; rp < 4; ++rp)
      part[(wid * 64 + cp * 16 + lg * 4 + rp) * 17 + lr] = oacc[cp][rp] * sc;
  __syncthreads();
  {
    int qq = threadIdx.x >> 5;          // 0..15
    int dv = (threadIdx.x & 31) * 2;    // 0,2,..,62
    float s0 = 0.f, s1 = 0.f;
#pragma unroll
    for (int w = 0; w < 8; ++w) {
      s0 += part[(w * 64 + dv) * 17 + qq];
      s1 += part[(w * 64 + dv + 1) * 17 + qq];
    }
    unsigned ow = pack_bf16(s0, s1);
    *(unsigned*)(oh + ((size_t)(b * SDIM + q0 + qq)) * DDIM + h * DH + dv) = ow;
  }
}

__global__ __launch_bounds__(512, 4) void fused_kernel_cov(const __bf16* __restrict__ qh,
                                                           const __bf16* __restrict__ kh,
                                                           const __bf16* __restrict__ vT,
                                                           const __bf16* __restrict__ covm,
                                                           const float* __restrict__ lam,
                                                           float* __restrict__ attn,
                                                           __bf16* __restrict__ oh,
                                                           const int* __restrict__ flag) {
  extern __shared__ float smem[];
  if (*flag == 1) fused_body<true>(qh, kh, vT, covm, lam, attn, oh, smem);
  else            fused_body<false>(qh, kh, vT, covm, lam, attn, oh, smem);
}

// ---- FC + residual: out = oh @ w_fc + q  (f32 out)
template <bool C1>
static __device__ __forceinline__ void fc_body(const __bf16* __restrict__ oh,
                                               const __bf16* __restrict__ wfcT,
                                               const float* __restrict__ resid,
                                               float* __restrict__ out) {
  int n0 = blockIdx.x * 64;
  int m0 = blockIdx.y * 64;
  int wid = threadIdx.x >> 6, lane = threadIdx.x & 63;
  int lr = lane & 15, lg = lane >> 4;
  int mrow = m0 + wid * 16;
  f32x4 acc[4] = {};
  for (int kb = 0; kb < DDIM; kb += 32) {
    bf16x8 afrag = *(const bf16x8*)(oh + (size_t)(mrow + lr) * DDIM + kb + lg * 8);
#pragma unroll
    for (int c = 0; c < 4; ++c) {
      bf16x8 bfrag = *(const bf16x8*)(wfcT + (size_t)(n0 + c * 16 + lr) * DDIM + kb + lg * 8);
      acc[c] = mf<C1>(afrag, bfrag, acc[c]);
    }
  }
#pragma unroll
  for (int c = 0; c < 4; ++c)
#pragma unroll
    for (int r = 0; r < 4; ++r) {
      size_t m = mrow + lg * 4 + r;
      size_t n = n0 + c * 16 + lr;
      out[m * DDIM + n] = acc[c][r] + resid[m * DDIM + n];
    }
}

__global__ __launch_bounds__(256) void fc_kernel(const __bf16* __restrict__ oh,
                                                 const __bf16* __restrict__ wfcT,
                                                 const float* __restrict__ resid,
                                                 float* __restrict__ out,
                                                 const int* __restrict__ flag) {
  if (*flag == 1) fc_body<true>(oh, wfcT, resid, out);
  else            fc_body<false>(oh, wfcT, resid, out);
}

extern "C" void kernel_launch(void* const* d_in, const int* in_sizes, int n_in,
                              void* d_out, int out_size, void* d_ws, size_t ws_size,
                              hipStream_t stream) {
  const float* q = (const float*)d_in[0];
  const float* k = (const float*)d_in[1];
  const float* v = (const float*)d_in[2];
  const float* static_cov = (const float*)d_in[3];
  const int* mask = (const int*)d_in[4];
  const float* w_q = (const float*)d_in[5];
  const float* w_k = (const float*)d_in[6];
  const float* w_v = (const float*)d_in[7];
  const float* w_fc = (const float*)d_in[8];
  const float* lam = (const float*)d_in[9];
  const float* gamma = (const float*)d_in[10];
  const float* beta = (const float*)d_in[11];

  float* out = (float*)d_out;
  float* attn = out + (size_t)2 * SDIM * DDIM;

  char* ws = (char*)d_ws;
  const size_t MB4 = (size_t)4 << 20;
  __bf16* qn  = (__bf16*)(ws);
  __bf16* qh  = (__bf16*)(ws + 1 * MB4);
  __bf16* kh  = (__bf16*)(ws + 2 * MB4);
  __bf16* vT  = (__bf16*)(ws + 3 * MB4);
  __bf16* oh  = (__bf16*)(ws + 4 * MB4);
  __bf16* wqT = (__bf16*)(ws + 5 * MB4);
  __bf16* wkT = (__bf16*)(ws + 5 * MB4 + 524288);
  __bf16* wvT = (__bf16*)(ws + 5 * MB4 + 2 * 524288);
  __bf16* wfcT= (__bf16*)(ws + 5 * MB4 + 3 * 524288);
  int* flag   = (int*)(ws + 5 * MB4 + 4 * 524288);
  __bf16* covm = (__bf16*)(ws + 6 * MB4);   // 16 MiB bf16, ends at 52 MiB

  const unsigned fused_smem = (8 * 64 * 17 + 128 + 128) * 4;   // 35,840 B
  const unsigned proj_smem  = 64 * 72 * 2;                     // 9,216 B

  stageB_kernel<<<dim3(1280), dim3(256), 0, stream>>>(q, gamma, beta, qn,
                                                      w_q, w_k, w_v, w_fc,
                                                      wqT, wkT, wvT, wfcT, flag);
  proj_kernel<<<dim3(64, 4, 4), dim3(256), proj_smem, stream>>>(qn, k, v, wqT, wkT, wvT, lam,
                                                                qh, kh, vT,
                                                                static_cov, mask, covm, flag);
  fused_kernel_cov<<<dim3(2048), dim3(512), fused_smem, stream>>>(qh, kh, vT, covm, lam, attn, oh, flag);
  fc_kernel<<<dim3(8, 64), dim3(256), 0, stream>>>(oh, wfcT, q, out, flag);
}